// Round 1
// 80.878 us; speedup vs baseline: 1.0426x; 1.0426x over previous
//
#include <hip/hip_runtime.h>

// Problem constants (from reference)
#define B        8192
#define N_IN     8
#define N_MFS    4
#define N_RULES  2048

#define THREADS  256
#define NB       32           // batches per block (R7: 32 halves total pack vs 16)
#define RSPLIT   8            // rule-groups: grid = (B/NB)*RSPLIT = 2048 blocks = 8/CU
#define RPB      (N_RULES / RSPLIT)   // 256 rules per block -> 1 rule/thread
#define LUT_W    101          // words per batch pair-LUT (100 used + 1 pad)
#define XS_W     (N_IN * N_MFS)       // 32 floats per batch

// R7 rationale:
//  - Baseline grid was 512 blocks = 2 blocks/CU = 2 waves/SIMD -> lgkmcnt
//    stalls before each store un-hidden, HBM write pipe starved.
//  - Pack total = (B/NB)*N_RULES is INVARIANT in rule-split -> multiply
//    blocks along the rule axis for free: NB=32 x RSPLIT=8 -> 2048 blocks,
//    32 waves/CU, and pack is now 1 rule/thread (trivial).
//  - x staged to LDS via one coalesced float4/thread; LUT build reads LDS
//    (kills ~25 scattered global loads per thread at block start).
//  - Gathers stay within one 25-word window per pair -> same-bank implies
//    same-word -> broadcast, conflict-free (baseline-verified, counter 0).
//  - Stores: 4B NT dword/lane, wave = 256B contiguous, full lines.
__global__ __launch_bounds__(THREADS) void fire_kernel(
        const float* __restrict__ x,
        const int*   __restrict__ mf,
        float* __restrict__ out)
{
    __shared__ float xs[NB * XS_W];      // 4 KB: 32 batches x 32 floats
    __shared__ float slut[NB * LUT_W];   // 12.9 KB: 32 batches x 101 words

    const int tid = threadIdx.x;
    const int rg  = blockIdx.x;          // rule group 0..7
    const int bg  = blockIdx.y;          // batch group 0..255
    const int b0  = bg * NB;
    const int r   = rg * RPB + tid;      // this thread's rule

    // ---- Stage this block's x slice: 1024 floats = 256 x float4, coalesced.
    {
        const float4* xg = (const float4*)(x + (size_t)b0 * XS_W);
        ((float4*)xs)[tid] = xg[tid];
    }

    // ---- Pack this thread's single rule into 4 word offsets (registers).
    int woff[4];
    {
        const int4* mr = (const int4*)(mf + (size_t)r * N_IN);
        const int4 lo = mr[0];
        const int4 hi = mr[1];
        const int idx[8] = {lo.x, lo.y, lo.z, lo.w, hi.x, hi.y, hi.z, hi.w};
#pragma unroll
        for (int p = 0; p < 4; ++p) {
            const int a = idx[2*p]   < 0 ? 4 : idx[2*p];
            const int b = idx[2*p+1] < 0 ? 4 : idx[2*p+1];
            woff[p] = p * 25 + a * 5 + b;
        }
    }
    __syncthreads();   // xs ready

    // ---- Build pair-product LUTs from LDS-resident x:
    //      slut[bl*101 + p*25 + a*5 + b] = va * vb  (a/b==4 -> 1.0)
    for (int e = tid; e < NB * 100; e += THREADS) {
        const int bl   = e / 100;
        const int rest = e - bl * 100;
        const int p    = rest / 25;
        const int c    = rest - p * 25;
        const int a    = c / 5;
        const int bb   = c - a * 5;
        const float* xb = xs + bl * XS_W;
        const float va = (a  < 4) ? xb[(2*p)   * N_MFS + a ] : 1.0f;
        const float vb = (bb < 4) ? xb[(2*p+1) * N_MFS + bb] : 1.0f;
        slut[bl * LUT_W + rest] = va * vb;
    }
    __syncthreads();   // slut ready

    // ---- Main loop: per batch, 4 ds_read_b32 (imm offset bl*404) + 3 muls
    //      + 1 NT dword store. Unroll 8 keeps ~32 live VGPRs (<=64 for
    //      32 waves/CU) while letting the scheduler batch reads/waits.
    float* o = out + (size_t)b0 * N_RULES + r;
#pragma unroll 8
    for (int bl = 0; bl < NB; ++bl) {
        const float* lb = slut + bl * LUT_W;
        const float v0 = lb[woff[0]];
        const float v1 = lb[woff[1]];
        const float v2 = lb[woff[2]];
        const float v3 = lb[woff[3]];
        const float res = (v0 * v1) * (v2 * v3);
        __builtin_nontemporal_store(res, o + (size_t)bl * N_RULES);
    }
}

extern "C" void kernel_launch(void* const* d_in, const int* in_sizes, int n_in,
                              void* d_out, int out_size, void* d_ws, size_t ws_size,
                              hipStream_t stream) {
    const float* x  = (const float*)d_in[0];   // (B, N_IN, N_MFS) fp32
    const int*   mf = (const int*)d_in[1];     // (N_RULES, N_IN) int32
    float* out = (float*)d_out;                // (B, N_RULES) fp32
    (void)d_ws; (void)ws_size;

    dim3 grid(RSPLIT, B / NB);
    fire_kernel<<<grid, THREADS, 0, stream>>>(x, mf, out);
}